// Round 1
// baseline (80.049 us; speedup 1.0000x reference)
//
#include <hip/hip_runtime.h>

// LogNorm moment-matching: mu/sigma of log-normal sum, per (state, gene).
// S=16 states, C=64 cell types, G=20000 genes. All fp32.
//
// Math per (s,g):
//   e_c   = exp(Z_mu[c,g] + 0.5*Z_sigma[c,g]^2)
//   Ssum  = sum_c w[s,c] * e_c
//   A_c   = w[s,c] * e_c * Z_sigma[c,g]
//   var   = (sum_{c,d} A_c corr[c,d] A_d) / Ssum^2
//         = (sum_c A_c^2 corr[c,c] + 2 sum_c A_c sum_{d<c} corr[c,d] A_d) / Ssum^2
//   mu    = log(Ssum) - 0.5*var ;  sigma = sqrt(var)
//
// Parallelization: one thread per (s,g). 320000 threads = 5000 waves.
// corr / cell_prob accesses are wave-uniform, compile-time-offset ->
// scalar loads (s_load) + SGPR operands in the FMAs. A[64] in VGPRs.

#define S_STATES 16
#define C_TYPES  64
#define G_GENES  20000

__global__ __launch_bounds__(256)
void lognorm_kernel(const float* __restrict__ Z_mu,
                    const float* __restrict__ Z_sigma,
                    const float* __restrict__ corr,
                    const float* __restrict__ cell_prob,
                    float* __restrict__ out)
{
    const int bid   = blockIdx.x;
    const int tile  = bid >> 2;                  // gene tile of 64
    const int squad = bid & 3;                   // state quarter
    const int lane  = threadIdx.x & 63;
    const int s     = squad * 4 + (threadIdx.x >> 6);
    const int g     = tile * 64 + lane;
    if (g >= G_GENES) return;

    const float* __restrict__ wrow = cell_prob + s * C_TYPES;  // uniform

    // ---- phase 1: e_c, Ssum, A_c ----
    float A[C_TYPES];
    float ss[4] = {0.f, 0.f, 0.f, 0.f};
#pragma unroll
    for (int c = 0; c < C_TYPES; ++c) {
        const float zm = Z_mu[c * G_GENES + g];
        const float zs = Z_sigma[c * G_GENES + g];
        const float e  = __expf(fmaf(0.5f * zs, zs, zm));
        const float w  = wrow[c];                 // scalar (wave-uniform)
        ss[c & 3] = fmaf(w, e, ss[c & 3]);
        A[c] = w * e * zs;
    }
    const float Ssum = (ss[0] + ss[1]) + (ss[2] + ss[3]);

    // ---- phase 2: triangular quadratic form ----
    float vacc[4] = {0.f, 0.f, 0.f, 0.f};
#pragma unroll
    for (int c = 0; c < C_TYPES; ++c) {
        const float* __restrict__ crow = corr + c * C_TYPES;  // uniform
        float b[4] = {0.f, 0.f, 0.f, 0.f};
#pragma unroll
        for (int d = 0; d < c; ++d)
            b[d & 3] = fmaf(crow[d], A[d], b[d & 3]);   // SGPR * VGPR fma
        const float bb = (b[0] + b[1]) + (b[2] + b[3]);
        // diagonal + off-diagonal contribution for this c
        vacc[c & 3] = fmaf(A[c] * crow[c], A[c], vacc[c & 3]);
        vacc[c & 3] = fmaf(2.0f * A[c], bb, vacc[c & 3]);
    }
    const float quad = (vacc[0] + vacc[1]) + (vacc[2] + vacc[3]);
    const float var  = quad / (Ssum * Ssum);

    const float mu = __logf(Ssum) - 0.5f * var;
    const float sg = sqrtf(var);

    out[s * G_GENES + g] = mu;
    out[S_STATES * G_GENES + s * G_GENES + g] = sg;
}

extern "C" void kernel_launch(void* const* d_in, const int* in_sizes, int n_in,
                              void* d_out, int out_size, void* d_ws, size_t ws_size,
                              hipStream_t stream) {
    const float* Z_mu      = (const float*)d_in[0];
    const float* Z_sigma   = (const float*)d_in[1];
    const float* corr      = (const float*)d_in[2];
    const float* cell_prob = (const float*)d_in[3];
    float* out = (float*)d_out;

    const int tiles = (G_GENES + 63) / 64;       // 313
    dim3 grid(tiles * 4);                        // 4 state-quarters per tile
    dim3 block(256);                             // 4 waves: 4 states x 64 genes
    lognorm_kernel<<<grid, block, 0, stream>>>(Z_mu, Z_sigma, corr, cell_prob, out);
}

// Round 2
// 30.586 us; speedup vs baseline: 2.6172x; 2.6172x over previous
//
#include <hip/hip_runtime.h>

// LogNorm moment-matching via bf16 MFMA.
//
// Math per (s,g):
//   e = exp(Z_mu + sigma^2/2); X1 = e; X2 = e*sigma          (C x G)
//   Ssum[s,g]    = sum_d w[s,d] X1[d,g]                       -> MFMA: W @ X1
//   R^s[c,d]     = w[s,c] corr[c,d] w[s,d]
//   B'[c,g]      = sum_d R^s[c,d] X2[d,g]                     -> MFMA: R^s @ X2
//   var_num[s,g] = sum_c X2[c,g] B'[c,g]                      -> VALU dot (LDS X2)
//   var = var_num / Ssum^2 ; mu = log(Ssum) - var/2 ; sigma = sqrt(var)
//
// Grid: 1250 gene-tiles (16 genes, exact) x 2 state-halves; block = 1 wave.
// MFMA 16x16x32 bf16. K-permutation shared by A/B frags cancels; C/D layout
// (col = lane&15, row = (lane>>4)*4 + reg) is the measured gfx950 mapping.

#define S_STATES 16
#define C_TYPES  64
#define G_GENES  20000

typedef __attribute__((ext_vector_type(8))) short bf16x8;
typedef __attribute__((ext_vector_type(4))) float f32x4;

static __device__ __forceinline__ short f2bf(float f) {
    union { float f; unsigned u; } v; v.f = f;
    unsigned r = v.u + 0x7fffu + ((v.u >> 16) & 1u);   // round-to-nearest-even
    return (short)(r >> 16);
}

__global__ __launch_bounds__(64, 2)
void lognorm_mfma(const float* __restrict__ Z_mu,
                  const float* __restrict__ Z_sigma,
                  const float* __restrict__ corr,
                  const float* __restrict__ w,
                  float* __restrict__ out)
{
    __shared__ float x2s[C_TYPES][17];   // f32 X2, 2-way-conflict-free reads

    const int bid  = blockIdx.x;
    const int gt   = bid >> 1;           // gene tile 0..1249
    const int sh   = bid & 1;            // state half 0..1
    const int lane = threadIdx.x;        // 0..63
    const int gl   = lane & 15;          // gene within tile == MFMA col
    const int q    = lane >> 4;          // k-block quarter
    const int g    = gt * 16 + gl;

    // ---- X-phase: each lane owns d = kb*32 + q*8 + j ----
    float x1v[2][8], x2v[2][8];
#pragma unroll
    for (int kb = 0; kb < 2; ++kb)
#pragma unroll
        for (int j = 0; j < 8; ++j) {
            const int d = kb * 32 + q * 8 + j;
            const float zm = Z_mu[d * G_GENES + g];
            const float zs = Z_sigma[d * G_GENES + g];
            const float e  = __expf(fmaf(0.5f * zs, zs, zm));
            x1v[kb][j] = e;
            x2v[kb][j] = e * zs;
            x2s[d][gl] = e * zs;
        }
    __syncthreads();   // single wave: orders ds_write -> ds_read

    // ---- pack B-operand frags (X1 for Ssum, X2 for var GEMM) ----
    bf16x8 x1f[2], x2f[2], wsf[2];
#pragma unroll
    for (int kb = 0; kb < 2; ++kb)
#pragma unroll
        for (int j = 0; j < 8; ++j) {
            x1f[kb][j] = f2bf(x1v[kb][j]);
            x2f[kb][j] = f2bf(x2v[kb][j]);
        }

    // ---- Ssum GEMM: A[m=s][k=d] = w[s][d]; all 16 states at once ----
#pragma unroll
    for (int kb = 0; kb < 2; ++kb) {
        const float* p = w + gl * C_TYPES + kb * 32 + q * 8;
        const float4 a = *(const float4*)p;
        const float4 b = *(const float4*)(p + 4);
        wsf[kb][0] = f2bf(a.x); wsf[kb][1] = f2bf(a.y);
        wsf[kb][2] = f2bf(a.z); wsf[kb][3] = f2bf(a.w);
        wsf[kb][4] = f2bf(b.x); wsf[kb][5] = f2bf(b.y);
        wsf[kb][6] = f2bf(b.z); wsf[kb][7] = f2bf(b.w);
    }
    f32x4 sacc = {0.f, 0.f, 0.f, 0.f};
    sacc = __builtin_amdgcn_mfma_f32_16x16x32_bf16(wsf[0], x1f[0], sacc, 0, 0, 0);
    sacc = __builtin_amdgcn_mfma_f32_16x16x32_bf16(wsf[1], x1f[1], sacc, 0, 0, 0);
    // lane holds Ssum[state = q*4+r][gene = gl]

    // ---- corr rows for the 4 output row-tiles (state-independent) ----
    float cr[4][2][8];
#pragma unroll
    for (int mt = 0; mt < 4; ++mt)
#pragma unroll
        for (int kb = 0; kb < 2; ++kb) {
            const float* p = corr + (mt * 16 + gl) * C_TYPES + kb * 32 + q * 8;
            const float4 a = *(const float4*)p;
            const float4 b = *(const float4*)(p + 4);
            cr[mt][kb][0] = a.x; cr[mt][kb][1] = a.y;
            cr[mt][kb][2] = a.z; cr[mt][kb][3] = a.w;
            cr[mt][kb][4] = b.x; cr[mt][kb][5] = b.y;
            cr[mt][kb][6] = b.z; cr[mt][kb][7] = b.w;
        }

    // ---- per-state: build A-frags of R^s, GEMM, dot, epilogue ----
#pragma unroll
    for (int si = 0; si < 8; ++si) {
        const int S = sh * 8 + si;
        const float* wrow = w + S * C_TYPES;

        float wc[4];
#pragma unroll
        for (int mt = 0; mt < 4; ++mt) wc[mt] = wrow[mt * 16 + gl];

        float wd[2][8];
#pragma unroll
        for (int kb = 0; kb < 2; ++kb) {
            const float* p = wrow + kb * 32 + q * 8;
            const float4 a = *(const float4*)p;
            const float4 b = *(const float4*)(p + 4);
            wd[kb][0] = a.x; wd[kb][1] = a.y; wd[kb][2] = a.z; wd[kb][3] = a.w;
            wd[kb][4] = b.x; wd[kb][5] = b.y; wd[kb][6] = b.z; wd[kb][7] = b.w;
        }

        f32x4 acc[4];
#pragma unroll
        for (int mt = 0; mt < 4; ++mt) acc[mt] = (f32x4){0.f, 0.f, 0.f, 0.f};

#pragma unroll
        for (int mt = 0; mt < 4; ++mt)
#pragma unroll
            for (int kb = 0; kb < 2; ++kb) {
                bf16x8 af;
#pragma unroll
                for (int j = 0; j < 8; ++j)
                    af[j] = f2bf(wc[mt] * cr[mt][kb][j] * wd[kb][j]);
                acc[mt] = __builtin_amdgcn_mfma_f32_16x16x32_bf16(
                    af, x2f[kb], acc[mt], 0, 0, 0);
            }

        // var dot over c: lane covers c = mt*16 + q*4 + r
        float vp = 0.f;
#pragma unroll
        for (int mt = 0; mt < 4; ++mt)
#pragma unroll
            for (int r = 0; r < 4; ++r)
                vp = fmaf(x2s[mt * 16 + q * 4 + r][gl], acc[mt][r], vp);
        vp += __shfl_xor(vp, 16);
        vp += __shfl_xor(vp, 32);

        const float ss   = __shfl(sacc[si & 3], ((S >> 2) * 16) + gl);
        const float rvar = fmaxf(vp, 0.f) / (ss * ss);
        const float muv  = __logf(ss) - 0.5f * rvar;
        const float sgv  = sqrtf(rvar);

        if (lane < 16)
            out[S * G_GENES + g] = muv;
        else if (lane < 32)
            out[S_STATES * G_GENES + S * G_GENES + g] = sgv;
    }
}

extern "C" void kernel_launch(void* const* d_in, const int* in_sizes, int n_in,
                              void* d_out, int out_size, void* d_ws, size_t ws_size,
                              hipStream_t stream) {
    const float* Z_mu      = (const float*)d_in[0];
    const float* Z_sigma   = (const float*)d_in[1];
    const float* corr      = (const float*)d_in[2];
    const float* cell_prob = (const float*)d_in[3];
    float* out = (float*)d_out;

    const int gtiles = G_GENES / 16;          // 1250, exact
    dim3 grid(gtiles * 2);                    // x2 state halves
    dim3 block(64);                           // one wave
    lognorm_mfma<<<grid, block, 0, stream>>>(Z_mu, Z_sigma, corr, cell_prob, out);
}

// Round 3
// 29.578 us; speedup vs baseline: 2.7063x; 1.0341x over previous
//
#include <hip/hip_runtime.h>
#include <hip/hip_bf16.h>

// LogNorm moment-matching via bf16 MFMA, v3.
//
//   e = exp(Z_mu + sigma^2/2); X1 = e; X2 = e*sigma              (C x G)
//   Ssum[s,g]    = sum_d w[s,d] X1[d,g]          -> MFMA: W @ X1 (all 16 s)
//   P[d,g]       = w[s,d] * X2[d,g]              (per state)
//   Y[c,g]       = sum_d corr[c,d] P[d,g]        -> MFMA: corr @ P
//   var_num[s,g] = sum_c P[c,g] Y[c,g]           -> VALU dot (w * LDS X2 * Y)
//   var = var_num/Ssum^2 ; mu = log(Ssum)-var/2 ; sigma = sqrt(var)
//
// Key change vs v2: corr (state-independent) is the A-operand, so the
// per-state rebuild is only the 16-elem B-frag (1 mul + cvt each), not a
// 64-elem R^s A-frag. 4 states/wave -> 5000 waves (4.9/SIMD) for latency
// hiding; Z re-reads are L2/L3-resident (10 MB inputs).
//
// MFMA 16x16x32 bf16, layout as verified in v2 (passed):
//   A-frag: lane(q,gl) holds A[m=gl, k=kb*32+q*8+j]
//   B-frag: lane(q,gl) holds B[k=kb*32+q*8+j, n=gl]
//   C/D:    lane(q,gl) reg r = D[row=q*4+r, col=gl]

#define S_STATES 16
#define C_TYPES  64
#define G_GENES  20000

typedef __attribute__((ext_vector_type(8))) short bf16x8;
typedef __attribute__((ext_vector_type(4))) float f32x4;

static __device__ __forceinline__ short f2bf(float f) {
    __hip_bfloat16 h = __float2bfloat16(f);   // RNE; compiler packs pairs
    union { __hip_bfloat16 h; short s; } u; u.h = h;
    return u.s;
}

__global__ __launch_bounds__(64, 4)
void lognorm_mfma(const float* __restrict__ Z_mu,
                  const float* __restrict__ Z_sigma,
                  const float* __restrict__ corr,
                  const float* __restrict__ w,
                  float* __restrict__ out)
{
    __shared__ float x2s[C_TYPES][17];   // X2 f32; 2-way conflicts only (free)

    const int bid  = blockIdx.x;
    const int gt   = bid >> 2;           // gene tile 0..1249
    const int sg   = bid & 3;            // state quad 0..3
    const int lane = threadIdx.x;
    const int gl   = lane & 15;          // gene within tile == MFMA col
    const int q    = lane >> 4;          // k quarter
    const int g    = gt * 16 + gl;

    // ---- X-phase: lane owns d = kb*32 + q*8 + j ----
    float x2v[2][8];
    bf16x8 x1f[2], x2f[2];
#pragma unroll
    for (int kb = 0; kb < 2; ++kb)
#pragma unroll
        for (int j = 0; j < 8; ++j) {
            const int d = kb * 32 + q * 8 + j;
            const float zm = Z_mu[d * G_GENES + g];
            const float zs = Z_sigma[d * G_GENES + g];
            const float e  = __expf(fmaf(0.5f * zs, zs, zm));
            const float x2 = e * zs;
            x1f[kb][j] = f2bf(e);
            x2f[kb][j] = f2bf(x2);
            x2v[kb][j] = x2;
            x2s[d][gl] = x2;
        }
    __syncthreads();   // orders ds_write -> ds_read (single wave)

    // ---- Ssum GEMM for all 16 states: A[m=s][k=d] = w ----
    bf16x8 wsf[2];
#pragma unroll
    for (int kb = 0; kb < 2; ++kb) {
        const float* p = w + gl * C_TYPES + kb * 32 + q * 8;
        const float4 a = *(const float4*)p;
        const float4 b = *(const float4*)(p + 4);
        wsf[kb][0] = f2bf(a.x); wsf[kb][1] = f2bf(a.y);
        wsf[kb][2] = f2bf(a.z); wsf[kb][3] = f2bf(a.w);
        wsf[kb][4] = f2bf(b.x); wsf[kb][5] = f2bf(b.y);
        wsf[kb][6] = f2bf(b.z); wsf[kb][7] = f2bf(b.w);
    }
    f32x4 sacc = {0.f, 0.f, 0.f, 0.f};
    sacc = __builtin_amdgcn_mfma_f32_16x16x32_bf16(wsf[0], x1f[0], sacc, 0, 0, 0);
    sacc = __builtin_amdgcn_mfma_f32_16x16x32_bf16(wsf[1], x1f[1], sacc, 0, 0, 0);
    // Ssum[state=q*4+r][gene=gl] in sacc[r]

    // ---- state-independent A-operand: bf16(corr) frags ----
    bf16x8 corrf[4][2];
#pragma unroll
    for (int mt = 0; mt < 4; ++mt)
#pragma unroll
        for (int kb = 0; kb < 2; ++kb) {
            const float* p = corr + (mt * 16 + gl) * C_TYPES + kb * 32 + q * 8;
            const float4 a = *(const float4*)p;
            const float4 b = *(const float4*)(p + 4);
            corrf[mt][kb][0] = f2bf(a.x); corrf[mt][kb][1] = f2bf(a.y);
            corrf[mt][kb][2] = f2bf(a.z); corrf[mt][kb][3] = f2bf(a.w);
            corrf[mt][kb][4] = f2bf(b.x); corrf[mt][kb][5] = f2bf(b.y);
            corrf[mt][kb][6] = f2bf(b.z); corrf[mt][kb][7] = f2bf(b.w);
        }

    // ---- 4 states: B = bf16(w o X2), GEMM, dot, epilogue ----
#pragma unroll
    for (int si = 0; si < 4; ++si) {
        const int S = sg * 4 + si;
        const float* wrow = w + S * C_TYPES;

        // B-frags P = w o X2
        bf16x8 pb[2];
#pragma unroll
        for (int kb = 0; kb < 2; ++kb) {
            const float* p = wrow + kb * 32 + q * 8;
            const float4 a = *(const float4*)p;
            const float4 b = *(const float4*)(p + 4);
            pb[kb][0] = f2bf(a.x * x2v[kb][0]); pb[kb][1] = f2bf(a.y * x2v[kb][1]);
            pb[kb][2] = f2bf(a.z * x2v[kb][2]); pb[kb][3] = f2bf(a.w * x2v[kb][3]);
            pb[kb][4] = f2bf(b.x * x2v[kb][4]); pb[kb][5] = f2bf(b.y * x2v[kb][5]);
            pb[kb][6] = f2bf(b.z * x2v[kb][6]); pb[kb][7] = f2bf(b.w * x2v[kb][7]);
        }

        f32x4 acc[4];
#pragma unroll
        for (int mt = 0; mt < 4; ++mt) acc[mt] = (f32x4){0.f, 0.f, 0.f, 0.f};
#pragma unroll
        for (int mt = 0; mt < 4; ++mt) {
            acc[mt] = __builtin_amdgcn_mfma_f32_16x16x32_bf16(corrf[mt][0], pb[0], acc[mt], 0, 0, 0);
            acc[mt] = __builtin_amdgcn_mfma_f32_16x16x32_bf16(corrf[mt][1], pb[1], acc[mt], 0, 0, 0);
        }

        // var dot over c: lane covers c = mt*16 + q*4 + r
        float vp = 0.f;
#pragma unroll
        for (int mt = 0; mt < 4; ++mt) {
            const int c0 = mt * 16 + q * 4;
            const float4 wq = *(const float4*)(wrow + c0);   // w[S, c0..c0+3]
            vp = fmaf(wq.x * x2s[c0 + 0][gl], acc[mt][0], vp);
            vp = fmaf(wq.y * x2s[c0 + 1][gl], acc[mt][1], vp);
            vp = fmaf(wq.z * x2s[c0 + 2][gl], acc[mt][2], vp);
            vp = fmaf(wq.w * x2s[c0 + 3][gl], acc[mt][3], vp);
        }
        vp += __shfl_xor(vp, 16);
        vp += __shfl_xor(vp, 32);

        const float ss   = __shfl(sacc[si], sg * 16 + gl);   // Ssum[S][g]
        const float rvar = fmaxf(vp, 0.f) / (ss * ss);
        const float muv  = __logf(ss) - 0.5f * rvar;
        const float sgv  = sqrtf(rvar);

        if (lane < 16)
            out[S * G_GENES + g] = muv;
        else if (lane < 32)
            out[S_STATES * G_GENES + S * G_GENES + g] = sgv;
    }
}

extern "C" void kernel_launch(void* const* d_in, const int* in_sizes, int n_in,
                              void* d_out, int out_size, void* d_ws, size_t ws_size,
                              hipStream_t stream) {
    const float* Z_mu      = (const float*)d_in[0];
    const float* Z_sigma   = (const float*)d_in[1];
    const float* corr      = (const float*)d_in[2];
    const float* cell_prob = (const float*)d_in[3];
    float* out = (float*)d_out;

    const int gtiles = G_GENES / 16;          // 1250, exact
    dim3 grid(gtiles * 4);                    // x4 state quads
    dim3 block(64);                           // one wave
    lognorm_mfma<<<grid, block, 0, stream>>>(Z_mu, Z_sigma, corr, cell_prob, out);
}

// Round 4
// 27.392 us; speedup vs baseline: 2.9224x; 1.0798x over previous
//
#include <hip/hip_runtime.h>

// LogNorm moment-matching via bf16 MFMA, v4: precomputed frag-ordered R^s.
//
//   e = exp(Z_mu + sigma^2/2); X1 = e; X2 = e*sigma              (C x G)
//   Ssum[s,g]    = sum_d w[s,d] X1[d,g]        -> MFMA: W @ X1 (all 16 s)
//   R^s[c,d]     = w[s,c] corr[c,d] w[s,d]     -> PRECOMPUTED bf16, frag-ordered
//   Y[c,g]       = sum_d R^s[c,d] X2[d,g]      -> MFMA: R^s @ X2
//   var_num[s,g] = sum_c X2[c,g] Y[c,g]        -> VALU dot (LDS X2)
//   var = var_num/Ssum^2 ; mu = log(Ssum)-var/2 ; sigma = sqrt(var)
//
// v3 post-mortem: ~40 cyc/inst -> register-pressure-serialized load chains.
// Fix: A-frags (R^s) built once in a 128-wave precompute kernel (128 KB in
// d_ws, L2-resident); main kernel loads them as coalesced dwordx4 with
// addresses known at entry (deep prefetch), peak VGPR ~90, no per-state
// frag construction VALU.
//
// MFMA 16x16x32 bf16 layout (verified by v2/v3 passing):
//   A-frag: lane(q,gl) holds A[m=gl][k=kb*32+q*8+j]
//   B-frag: lane(q,gl) holds B[k=kb*32+q*8+j][n=gl]
//   C/D:    lane(q,gl) reg r = D[row=q*4+r][col=gl]

#define S_STATES 16
#define C_TYPES  64
#define G_GENES  20000

typedef __attribute__((ext_vector_type(8))) short bf16x8;
typedef __attribute__((ext_vector_type(4))) float f32x4;

static __device__ __forceinline__ short f2bf(float f) {
    union { float f; unsigned u; } v; v.f = f;
    unsigned r = v.u + 0x7fffu + ((v.u >> 16) & 1u);   // RNE
    return (short)(r >> 16);
}

// ---- Kernel P: build frag-ordered bf16 R^s panels ----
// panel bid = s*8 + mt*2 + kb : 64 lanes x 16 B = 1 KB each; 128 KB total.
__global__ __launch_bounds__(64)
void build_cw(const float* __restrict__ corr, const float* __restrict__ w,
              short* __restrict__ cw)
{
    const int bid  = blockIdx.x;
    const int s    = bid >> 3;
    const int mt   = (bid >> 1) & 3;
    const int kb   = bid & 1;
    const int lane = threadIdx.x;
    const int gl   = lane & 15;
    const int q    = lane >> 4;
    const int row  = mt * 16 + gl;          // c index (A-row)
    const int k0   = kb * 32 + q * 8;       // d index base (A-col)

    const float  wc = w[s * C_TYPES + row];
    const float4 c0 = *(const float4*)(corr + row * C_TYPES + k0);
    const float4 c1 = *(const float4*)(corr + row * C_TYPES + k0 + 4);
    const float4 w0 = *(const float4*)(w + s * C_TYPES + k0);
    const float4 w1 = *(const float4*)(w + s * C_TYPES + k0 + 4);

    bf16x8 v;
    v[0] = f2bf(wc * c0.x * w0.x); v[1] = f2bf(wc * c0.y * w0.y);
    v[2] = f2bf(wc * c0.z * w0.z); v[3] = f2bf(wc * c0.w * w0.w);
    v[4] = f2bf(wc * c1.x * w1.x); v[5] = f2bf(wc * c1.y * w1.y);
    v[6] = f2bf(wc * c1.z * w1.z); v[7] = f2bf(wc * c1.w * w1.w);

    *(bf16x8*)(cw + (bid << 9) + lane * 8) = v;
}

// ---- Kernel M: main ----
__global__ __launch_bounds__(64, 4)
void lognorm_main(const float* __restrict__ Z_mu,
                  const float* __restrict__ Z_sigma,
                  const float* __restrict__ w,
                  const short* __restrict__ cw,
                  float* __restrict__ out)
{
    __shared__ float x2s[C_TYPES][20];   // stride 20: dot reads exactly 2-way

    const int bid  = blockIdx.x;
    const int gt   = bid >> 2;           // gene tile 0..1249
    const int sg   = bid & 3;            // state quad 0..3
    const int lane = threadIdx.x;
    const int gl   = lane & 15;          // gene within tile == MFMA col
    const int q    = lane >> 4;          // k quarter
    const int g    = gt * 16 + gl;

    // ---- X-phase: lane owns d = kb*32 + q*8 + j ----
    bf16x8 x1f[2], x2f[2];
#pragma unroll
    for (int kb = 0; kb < 2; ++kb)
#pragma unroll
        for (int j = 0; j < 8; ++j) {
            const int d = kb * 32 + q * 8 + j;
            const float zm = Z_mu[d * G_GENES + g];
            const float zs = Z_sigma[d * G_GENES + g];
            const float e  = __expf(fmaf(0.5f * zs, zs, zm));
            const float x2 = e * zs;
            x1f[kb][j] = f2bf(e);
            x2f[kb][j] = f2bf(x2);
            x2s[d][gl] = x2;
        }
    __syncthreads();

    // ---- Ssum GEMM for all 16 states: A[m=state][k=d] = w ----
    bf16x8 wsf[2];
#pragma unroll
    for (int kb = 0; kb < 2; ++kb) {
        const float* p = w + gl * C_TYPES + kb * 32 + q * 8;
        const float4 a = *(const float4*)p;
        const float4 b = *(const float4*)(p + 4);
        wsf[kb][0] = f2bf(a.x); wsf[kb][1] = f2bf(a.y);
        wsf[kb][2] = f2bf(a.z); wsf[kb][3] = f2bf(a.w);
        wsf[kb][4] = f2bf(b.x); wsf[kb][5] = f2bf(b.y);
        wsf[kb][6] = f2bf(b.z); wsf[kb][7] = f2bf(b.w);
    }
    f32x4 sacc = {0.f, 0.f, 0.f, 0.f};
    sacc = __builtin_amdgcn_mfma_f32_16x16x32_bf16(wsf[0], x1f[0], sacc, 0, 0, 0);
    sacc = __builtin_amdgcn_mfma_f32_16x16x32_bf16(wsf[1], x1f[1], sacc, 0, 0, 0);
    // Ssum[state=q*4+r][gene=gl] in sacc[r]

    // ---- 4 states: load R^s frags (pure coalesced loads), GEMM, dot ----
#pragma unroll
    for (int si = 0; si < 4; ++si) {
        const int S = sg * 4 + si;

        bf16x8 af[4][2];
#pragma unroll
        for (int mt = 0; mt < 4; ++mt)
#pragma unroll
            for (int kb = 0; kb < 2; ++kb)
                af[mt][kb] = *(const bf16x8*)(
                    cw + ((S * 8 + mt * 2 + kb) << 9) + lane * 8);

        f32x4 acc[4];
#pragma unroll
        for (int mt = 0; mt < 4; ++mt) acc[mt] = (f32x4){0.f, 0.f, 0.f, 0.f};
#pragma unroll
        for (int mt = 0; mt < 4; ++mt) {
            acc[mt] = __builtin_amdgcn_mfma_f32_16x16x32_bf16(af[mt][0], x2f[0], acc[mt], 0, 0, 0);
            acc[mt] = __builtin_amdgcn_mfma_f32_16x16x32_bf16(af[mt][1], x2f[1], acc[mt], 0, 0, 0);
        }

        // var dot over c: lane covers c = mt*16 + q*4 + r
        float vp = 0.f;
#pragma unroll
        for (int mt = 0; mt < 4; ++mt) {
            const int c0 = mt * 16 + q * 4;
            vp = fmaf(x2s[c0 + 0][gl], acc[mt][0], vp);
            vp = fmaf(x2s[c0 + 1][gl], acc[mt][1], vp);
            vp = fmaf(x2s[c0 + 2][gl], acc[mt][2], vp);
            vp = fmaf(x2s[c0 + 3][gl], acc[mt][3], vp);
        }
        vp += __shfl_xor(vp, 16);
        vp += __shfl_xor(vp, 32);

        const float ss   = __shfl(sacc[si], sg * 16 + gl);   // Ssum[S][g]
        const float rvar = fmaxf(vp, 0.f) / (ss * ss);
        const float muv  = __logf(ss) - 0.5f * rvar;
        const float sgv  = sqrtf(rvar);

        if (lane < 16)
            out[S * G_GENES + g] = muv;
        else if (lane < 32)
            out[S_STATES * G_GENES + S * G_GENES + g] = sgv;
    }
}

extern "C" void kernel_launch(void* const* d_in, const int* in_sizes, int n_in,
                              void* d_out, int out_size, void* d_ws, size_t ws_size,
                              hipStream_t stream) {
    const float* Z_mu      = (const float*)d_in[0];
    const float* Z_sigma   = (const float*)d_in[1];
    const float* corr      = (const float*)d_in[2];
    const float* cell_prob = (const float*)d_in[3];
    float* out = (float*)d_out;
    short* cw  = (short*)d_ws;                // 128 KB frag-ordered bf16 R^s

    build_cw<<<dim3(S_STATES * 8), dim3(64), 0, stream>>>(corr, cell_prob, cw);

    const int gtiles = G_GENES / 16;          // 1250, exact
    lognorm_main<<<dim3(gtiles * 4), dim3(64), 0, stream>>>(
        Z_mu, Z_sigma, cell_prob, cw, out);
}

// Round 5
// 22.249 us; speedup vs baseline: 3.5979x; 1.2311x over previous
//
#include <hip/hip_runtime.h>

// LogNorm moment-matching, v5: single flat-K GEMM over the (c,d) pair space.
//
//   e = exp(Z_mu + sigma^2/2); x1 = e; x2 = e*sigma               (C x G)
//   var_num[s,g] = sum_{c,d} (w_sc w_sd corr_cd) * (x2_c x2_d)
//                = GEMM: A[16 x 4096] @ B[4096 x G]
//     A precomputed frag-ordered bf16 in d_ws (130 KB, L2-resident)
//     B built in-register: B[p,g] = x2[c,g]*x2[d,g], p=(c,d)
//   Ssum[s,g]    = W @ x1  (2-kb GEMM, wave 0, W frags precomputed)
//   var = var_num/Ssum^2 ; mu = log(Ssum)-var/2 ; sigma = sqrt(var)
//
// K-index map: ki in [0,128): c = ki>>1, d = (ki&1)*32 + q*8 + j.
// Block = 256 thr (4 waves), one 16-gene tile; wave w owns ki = w*32..+31.
// K-split reduced through LDS; epilogue once per (s,g). No per-state loops,
// no per-state shuffles, no memory on the inner-loop critical path.
//
// MFMA 16x16x32 bf16 layout (verified v2-v4):
//   A-frag: lane(q,gl) = A[m=gl][k=ki*32+q*8+j]   (m = state)
//   B-frag: lane(q,gl) = B[k=ki*32+q*8+j][n=gl]   (n = gene)
//   C/D:    lane(q,gl) reg r = D[row=q*4+r][col=gl]

#define S_STATES 16
#define C_TYPES  64
#define G_GENES  20000
#define OUT_HALF (S_STATES * G_GENES)

typedef __attribute__((ext_vector_type(8))) short bf16x8;
typedef __attribute__((ext_vector_type(4))) float f32x4;

static __device__ __forceinline__ short f2bf(float f) {
    union { float f; unsigned u; } v; v.f = f;
    unsigned r = v.u + 0x7fffu + ((v.u >> 16) & 1u);   // RNE
    return (short)(r >> 16);
}

// ---- Kernel P: build frag-ordered A panels (1 KB each) ----
// ki < 128 : pair panels  A[s][ki*32+q*8+j] = w_sc * w_sd * corr_cd
// ki = 128,129 : W panels for the Ssum GEMM.
__global__ __launch_bounds__(64)
void build_A(const float* __restrict__ corr, const float* __restrict__ w,
             short* __restrict__ cwA)
{
    const int ki   = blockIdx.x;
    const int lane = threadIdx.x;
    const int gl   = lane & 15;          // state (A row)
    const int q    = lane >> 4;
    bf16x8 v;
    if (ki < 128) {
        const int c  = ki >> 1;
        const int d0 = (ki & 1) * 32 + q * 8;
        const float  wc = w[gl * C_TYPES + c];
        const float4 w0 = *(const float4*)(w + gl * C_TYPES + d0);
        const float4 w1 = *(const float4*)(w + gl * C_TYPES + d0 + 4);
        const float4 c0 = *(const float4*)(corr + c * C_TYPES + d0);
        const float4 c1 = *(const float4*)(corr + c * C_TYPES + d0 + 4);
        v[0] = f2bf(wc * c0.x * w0.x); v[1] = f2bf(wc * c0.y * w0.y);
        v[2] = f2bf(wc * c0.z * w0.z); v[3] = f2bf(wc * c0.w * w0.w);
        v[4] = f2bf(wc * c1.x * w1.x); v[5] = f2bf(wc * c1.y * w1.y);
        v[6] = f2bf(wc * c1.z * w1.z); v[7] = f2bf(wc * c1.w * w1.w);
    } else {
        const int k0 = (ki - 128) * 32 + q * 8;
        const float4 w0 = *(const float4*)(w + gl * C_TYPES + k0);
        const float4 w1 = *(const float4*)(w + gl * C_TYPES + k0 + 4);
        v[0] = f2bf(w0.x); v[1] = f2bf(w0.y); v[2] = f2bf(w0.z); v[3] = f2bf(w0.w);
        v[4] = f2bf(w1.x); v[5] = f2bf(w1.y); v[6] = f2bf(w1.z); v[7] = f2bf(w1.w);
    }
    *(bf16x8*)(cwA + (ki << 9) + lane * 8) = v;
}

// ---- Kernel M: main ----
__global__ __launch_bounds__(256, 4)
void lognorm_main(const float* __restrict__ Z_mu,
                  const float* __restrict__ Z_sigma,
                  const short* __restrict__ cwA,
                  float* __restrict__ out)
{
    __shared__ float x1s[C_TYPES][17];     // stride 17: q-quarters hit
    __shared__ float x2s[C_TYPES][17];     //   distinct bank groups
    __shared__ float accs[4][16][17];
    __shared__ float ssum_s[16][17];

    const int gt   = blockIdx.x;           // gene tile (16 genes, exact)
    const int tid  = threadIdx.x;
    const int w    = tid >> 6;             // wave id = K-chunk
    const int lane = tid & 63;
    const int gl   = lane & 15;            // gene within tile (MFMA col)
    const int q    = lane >> 4;

    // ---- X-phase (once per tile): thread -> (d = tid>>2, 4 genes) ----
    {
        const int d  = tid >> 2;
        const int g0 = (tid & 3) * 4;
        const float4 m4 = *(const float4*)(Z_mu    + d * G_GENES + gt * 16 + g0);
        const float4 s4 = *(const float4*)(Z_sigma + d * G_GENES + gt * 16 + g0);
        float e;
        e = __expf(fmaf(0.5f * s4.x, s4.x, m4.x)); x1s[d][g0+0] = e; x2s[d][g0+0] = e * s4.x;
        e = __expf(fmaf(0.5f * s4.y, s4.y, m4.y)); x1s[d][g0+1] = e; x2s[d][g0+1] = e * s4.y;
        e = __expf(fmaf(0.5f * s4.z, s4.z, m4.z)); x1s[d][g0+2] = e; x2s[d][g0+2] = e * s4.z;
        e = __expf(fmaf(0.5f * s4.w, s4.w, m4.w)); x1s[d][g0+3] = e; x2s[d][g0+3] = e * s4.w;
    }
    __syncthreads();

    // ---- per-lane B sources (all reg-resident, compile-time indexed) ----
    float x2c[16];                         // x2[c][gl], c = w*16 + ii
#pragma unroll
    for (int ii = 0; ii < 16; ++ii) x2c[ii] = x2s[w * 16 + ii][gl];
    float x2h[2][8];                       // x2[h*32 + q*8 + j][gl]
#pragma unroll
    for (int h = 0; h < 2; ++h)
#pragma unroll
        for (int j = 0; j < 8; ++j) x2h[h][j] = x2s[h * 32 + q * 8 + j][gl];

    // ---- K-loop: 32 kbs, {A-load, 8 mul, 8 cvt, MFMA}, 2 acc chains ----
    const short* Abase = cwA + ((w * 32) << 9) + lane * 8;
    f32x4 acc0 = {0.f, 0.f, 0.f, 0.f}, acc1 = {0.f, 0.f, 0.f, 0.f};
#pragma unroll
    for (int i = 0; i < 32; ++i) {
        const bf16x8 af = *(const bf16x8*)(Abase + (i << 9));
        const int ii = i >> 1, h = i & 1;
        bf16x8 bf;
#pragma unroll
        for (int j = 0; j < 8; ++j) bf[j] = f2bf(x2c[ii] * x2h[h][j]);
        if (h) acc1 = __builtin_amdgcn_mfma_f32_16x16x32_bf16(af, bf, acc1, 0, 0, 0);
        else   acc0 = __builtin_amdgcn_mfma_f32_16x16x32_bf16(af, bf, acc0, 0, 0, 0);
    }
    const f32x4 vsum = acc0 + acc1;
#pragma unroll
    for (int r = 0; r < 4; ++r) accs[w][q * 4 + r][gl] = vsum[r];

    // ---- wave 0: Ssum GEMM (K=64) ----
    if (w == 0) {
        bf16x8 x1f[2], wf[2];
#pragma unroll
        for (int kk = 0; kk < 2; ++kk) {
            wf[kk] = *(const bf16x8*)(cwA + ((128 + kk) << 9) + lane * 8);
#pragma unroll
            for (int j = 0; j < 8; ++j)
                x1f[kk][j] = f2bf(x1s[kk * 32 + q * 8 + j][gl]);
        }
        f32x4 sa = {0.f, 0.f, 0.f, 0.f};
        sa = __builtin_amdgcn_mfma_f32_16x16x32_bf16(wf[0], x1f[0], sa, 0, 0, 0);
        sa = __builtin_amdgcn_mfma_f32_16x16x32_bf16(wf[1], x1f[1], sa, 0, 0, 0);
#pragma unroll
        for (int r = 0; r < 4; ++r) ssum_s[q * 4 + r][gl] = sa[r];
    }
    __syncthreads();

    // ---- epilogue (once per (s,g)): thread -> (s = tid>>4, gx = tid&15) ----
    const int s  = tid >> 4;
    const int gx = tid & 15;
    const float vn = (accs[0][s][gx] + accs[1][s][gx])
                   + (accs[2][s][gx] + accs[3][s][gx]);
    const float ss   = ssum_s[s][gx];
    const float rvar = fmaxf(vn, 0.f) / (ss * ss);
    out[s * G_GENES + gt * 16 + gx]            = __logf(ss) - 0.5f * rvar;
    out[OUT_HALF + s * G_GENES + gt * 16 + gx] = sqrtf(rvar);
}

extern "C" void kernel_launch(void* const* d_in, const int* in_sizes, int n_in,
                              void* d_out, int out_size, void* d_ws, size_t ws_size,
                              hipStream_t stream) {
    const float* Z_mu      = (const float*)d_in[0];
    const float* Z_sigma   = (const float*)d_in[1];
    const float* corr      = (const float*)d_in[2];
    const float* cell_prob = (const float*)d_in[3];
    float* out = (float*)d_out;
    short* cwA = (short*)d_ws;                 // 130 KB frag-ordered A

    build_A<<<dim3(130), dim3(64), 0, stream>>>(corr, cell_prob, cwA);

    const int gtiles = G_GENES / 16;           // 1250, exact
    lognorm_main<<<dim3(gtiles), dim3(256), 0, stream>>>(
        Z_mu, Z_sigma, cwA, out);
}

// Round 6
// 17.286 us; speedup vs baseline: 4.6308x; 1.2871x over previous
//
#include <hip/hip_runtime.h>
#include <hip/hip_bf16.h>

// LogNorm moment-matching, v6: triangular flat-K GEMM, 32 genes/block.
//
//   e = exp(Z_mu + sigma^2/2); x1 = e; x2 = e*sigma               (C x G)
//   var_num[s,g] = sum_{d<=c} scale * (w_sc w_sd corr_cd) * (x2_c x2_d),
//                  scale = 2 for d<c, 1 for d=c   (symmetry fold)
//   -> GEMM: A[16 x 3072] @ B[3072 x G]; A precomputed frag-ordered bf16.
//   Ssum[s,g] = W @ x1 (2 extra panels); var = var_num/Ssum^2;
//   mu = log(Ssum) - var/2 ; sigma = sqrt(var)
//
// Panels: 96 nonzero (c,dhalf) pairs: p<64 -> (c=p, dh=0); p>=64 ->
// (c=p-32, dh=1). Wave w takes p = i*4+w, i in [0,24); dh = (i>=16) is
// compile-time after unroll. Block = 256 thr, 32 genes (2 subtiles/wave):
// each A-load feeds 2 MFMAs. L2 A-traffic 60 MB total; K-split reduced
// via LDS; epilogue once per (s,g).
//
// MFMA 16x16x32 bf16 layout (verified v2-v5):
//   A-frag: lane(q,gl) = A[m=gl][k=q*8+j]  (m = state)
//   B-frag: lane(q,gl) = B[k=q*8+j][n=gl]  (n = gene)
//   C/D:    lane(q,gl) reg r = D[row=q*4+r][col=gl]

#define S_STATES 16
#define C_TYPES  64
#define G_GENES  20000
#define OUT_HALF (S_STATES * G_GENES)
#define NPAIR    96          // triangular panels
#define PER_WAVE 24          // panels per wave

typedef __attribute__((ext_vector_type(8))) short bf16x8;
typedef __attribute__((ext_vector_type(4))) float f32x4;

static __device__ __forceinline__ short f2bf(float f) {
    union { __hip_bfloat16 h; short s; } u;
    u.h = __float2bfloat16(f);           // RNE; compiler packs pairs
    return u.s;
}

// ---- Kernel P: build frag-ordered A panels (1 KB each; 98 KB total) ----
__global__ __launch_bounds__(64)
void build_A(const float* __restrict__ corr, const float* __restrict__ w,
             short* __restrict__ cwA)
{
    const int p    = blockIdx.x;         // 0..97
    const int lane = threadIdx.x;
    const int gl   = lane & 15;          // state (A row)
    const int q    = lane >> 4;
    bf16x8 v;
    if (p < NPAIR) {
        const int dh = (p >= 64);
        const int c  = dh ? p - 32 : p;
        const int d0 = dh * 32 + q * 8;
        const float wc = w[gl * C_TYPES + c];
#pragma unroll
        for (int j = 0; j < 8; ++j) {
            const int d = d0 + j;
            const float sc = (d < c) ? 2.0f : (d == c ? 1.0f : 0.0f);
            v[j] = f2bf(sc * corr[c * C_TYPES + d] * wc * w[gl * C_TYPES + d]);
        }
    } else {                              // W panels for Ssum GEMM
        const int k0 = (p - NPAIR) * 32 + q * 8;
#pragma unroll
        for (int j = 0; j < 8; ++j)
            v[j] = f2bf(w[gl * C_TYPES + k0 + j]);
    }
    *(bf16x8*)(cwA + (p << 9) + lane * 8) = v;
}

// ---- Kernel M: main ----
__global__ __launch_bounds__(256, 3)
void lognorm_main(const float* __restrict__ Z_mu,
                  const float* __restrict__ Z_sigma,
                  const short* __restrict__ cwA,
                  float* __restrict__ out)
{
    __shared__ float x1s[C_TYPES][33];   // stride 33: all reads 2-way/bcast
    __shared__ float x2s[C_TYPES][33];
    __shared__ float accs[4][S_STATES][33];
    __shared__ float ssum_s[S_STATES][33];

    const int gt    = blockIdx.x;        // 0..624, 32 genes each (exact)
    const int tid   = threadIdx.x;
    const int w     = tid >> 6;          // wave id = panel interleave slot
    const int lane  = tid & 63;
    const int gl    = lane & 15;
    const int q     = lane >> 4;
    const int gbase = gt * 32;

    // ---- X-phase: thread -> (d = tid>>2, 4+4 genes) ----
    {
        const int d  = tid >> 2;
        const int g0 = (tid & 3) * 4;
        const float* zm = Z_mu    + d * G_GENES + gbase + g0;
        const float* zs = Z_sigma + d * G_GENES + gbase + g0;
        const float4 m0 = *(const float4*)zm, m1 = *(const float4*)(zm + 16);
        const float4 s0 = *(const float4*)zs, s1 = *(const float4*)(zs + 16);
        float e;
        e = __expf(fmaf(0.5f*s0.x, s0.x, m0.x)); x1s[d][g0+0]    = e; x2s[d][g0+0]    = e*s0.x;
        e = __expf(fmaf(0.5f*s0.y, s0.y, m0.y)); x1s[d][g0+1]    = e; x2s[d][g0+1]    = e*s0.y;
        e = __expf(fmaf(0.5f*s0.z, s0.z, m0.z)); x1s[d][g0+2]    = e; x2s[d][g0+2]    = e*s0.z;
        e = __expf(fmaf(0.5f*s0.w, s0.w, m0.w)); x1s[d][g0+3]    = e; x2s[d][g0+3]    = e*s0.w;
        e = __expf(fmaf(0.5f*s1.x, s1.x, m1.x)); x1s[d][g0+16]   = e; x2s[d][g0+16]   = e*s1.x;
        e = __expf(fmaf(0.5f*s1.y, s1.y, m1.y)); x1s[d][g0+17]   = e; x2s[d][g0+17]   = e*s1.y;
        e = __expf(fmaf(0.5f*s1.z, s1.z, m1.z)); x1s[d][g0+18]   = e; x2s[d][g0+18]   = e*s1.z;
        e = __expf(fmaf(0.5f*s1.w, s1.w, m1.w)); x1s[d][g0+19]   = e; x2s[d][g0+19]   = e*s1.w;
    }
    __syncthreads();

    // ---- per-lane B sources (reg-resident, static-indexed) ----
    float xc[PER_WAVE][2];               // x2[c_i][gene(t)]
#pragma unroll
    for (int i = 0; i < PER_WAVE; ++i) {
        const int p = i * 4 + w;
        const int c = (i >= 16) ? p - 32 : p;
#pragma unroll
        for (int t = 0; t < 2; ++t) xc[i][t] = x2s[c][gl + t * 16];
    }
    float xh[2][8][2];                   // x2[dh*32+q*8+j][gene(t)]
#pragma unroll
    for (int dh = 0; dh < 2; ++dh)
#pragma unroll
        for (int j = 0; j < 8; ++j)
#pragma unroll
            for (int t = 0; t < 2; ++t)
                xh[dh][j][t] = x2s[dh * 32 + q * 8 + j][gl + t * 16];

    // ---- K-loop: 24 iters of {A-load, 2x(8 mul + 8 cvt), 2 MFMA} ----
    const short* Abase = cwA + (w << 9) + lane * 8;
    f32x4 acc0 = {0.f, 0.f, 0.f, 0.f}, acc1 = {0.f, 0.f, 0.f, 0.f};
#pragma unroll
    for (int i = 0; i < PER_WAVE; ++i) {
        const bf16x8 af = *(const bf16x8*)(Abase + (i << 11));
        const int dh = (i >= 16) ? 1 : 0;
        bf16x8 b0, b1;
#pragma unroll
        for (int j = 0; j < 8; ++j) {
            b0[j] = f2bf(xc[i][0] * xh[dh][j][0]);
            b1[j] = f2bf(xc[i][1] * xh[dh][j][1]);
        }
        acc0 = __builtin_amdgcn_mfma_f32_16x16x32_bf16(af, b0, acc0, 0, 0, 0);
        acc1 = __builtin_amdgcn_mfma_f32_16x16x32_bf16(af, b1, acc1, 0, 0, 0);
    }
#pragma unroll
    for (int r = 0; r < 4; ++r) {
        accs[w][q * 4 + r][gl]      = acc0[r];
        accs[w][q * 4 + r][gl + 16] = acc1[r];
    }

    // ---- Ssum GEMM: waves 0,1 cover gene subtiles 0,1 ----
    if (w < 2) {
        bf16x8 x1f[2], wf[2];
#pragma unroll
        for (int kk = 0; kk < 2; ++kk) {
            wf[kk] = *(const bf16x8*)(cwA + ((NPAIR + kk) << 9) + lane * 8);
#pragma unroll
            for (int j = 0; j < 8; ++j)
                x1f[kk][j] = f2bf(x1s[kk * 32 + q * 8 + j][gl + w * 16]);
        }
        f32x4 sa = {0.f, 0.f, 0.f, 0.f};
        sa = __builtin_amdgcn_mfma_f32_16x16x32_bf16(wf[0], x1f[0], sa, 0, 0, 0);
        sa = __builtin_amdgcn_mfma_f32_16x16x32_bf16(wf[1], x1f[1], sa, 0, 0, 0);
#pragma unroll
        for (int r = 0; r < 4; ++r) ssum_s[q * 4 + r][gl + w * 16] = sa[r];
    }
    __syncthreads();

    // ---- epilogue: thread -> (s = tid>>4, genes gx, gx+16) ----
    const int s  = tid >> 4;
    const int gx = tid & 15;
#pragma unroll
    for (int t = 0; t < 2; ++t) {
        const int gg = gx + t * 16;
        const float vn = (accs[0][s][gg] + accs[1][s][gg])
                       + (accs[2][s][gg] + accs[3][s][gg]);
        const float ss   = ssum_s[s][gg];
        const float rvar = fmaxf(vn, 0.f) / (ss * ss);
        out[s * G_GENES + gbase + gg]            = __logf(ss) - 0.5f * rvar;
        out[OUT_HALF + s * G_GENES + gbase + gg] = sqrtf(rvar);
    }
}

extern "C" void kernel_launch(void* const* d_in, const int* in_sizes, int n_in,
                              void* d_out, int out_size, void* d_ws, size_t ws_size,
                              hipStream_t stream) {
    const float* Z_mu      = (const float*)d_in[0];
    const float* Z_sigma   = (const float*)d_in[1];
    const float* corr      = (const float*)d_in[2];
    const float* cell_prob = (const float*)d_in[3];
    float* out = (float*)d_out;
    short* cwA = (short*)d_ws;                 // 98 KB frag-ordered A

    build_A<<<dim3(NPAIR + 2), dim3(64), 0, stream>>>(corr, cell_prob, cwA);

    const int gtiles = G_GENES / 32;           // 625, exact
    lognorm_main<<<dim3(gtiles), dim3(256), 0, stream>>>(
        Z_mu, Z_sigma, cwA, out);
}

// Round 7
// 15.405 us; speedup vs baseline: 5.1962x; 1.1221x over previous
//
#include <hip/hip_runtime.h>

// LogNorm moment-matching, v7: triangular flat-K GEMM in packed f16.
//
//   e = exp(Z_mu + sigma^2/2); x1' = e/4; x2' = e*sigma/4        (C x G)
//   var_num'[s,g] = sum_{d<=c} sc * (w_sc w_sd corr_cd) * (x2'_c x2'_d)
//   Ssum'[s,g]    = W @ x1'               (scale 1/4)
//   var = vn'/ss'^2 (scales cancel);  mu = log(ss') + log4 - var/2
//   sigma = sqrt(var)
//
// f16 path: A panels f16 (precomputed, frag-ordered, 98 KB d_ws);
// B built per K-step with 8 v_pk_mul_f16 (d-paired xh f16x2 from LDS,
// subtile-paired xc f16x2 with compile-time .x/.y splat). 1/4 pre-scale
// keeps all f16 products < 2100 (max 65504). f16 10-bit mantissa beats
// bf16 -> absmax should DROP (~1e-3); that's the correctness signal.
//
// MFMA 16x16x32_f16, layout identical to the verified bf16 runs:
//   A-frag: lane(q,gl) = A[m=gl][k=q*8+j]   (m = state)
//   B-frag: lane(q,gl) = B[k=q*8+j][n=gl]   (n = gene)
//   C/D:    lane(q,gl) reg r = D[row=q*4+r][col=gl]

#define S_STATES 16
#define C_TYPES  64
#define G_GENES  20000
#define OUT_HALF (S_STATES * G_GENES)
#define NPAIR    96
#define PER_WAVE 24

typedef _Float16 f16x2 __attribute__((ext_vector_type(2)));
typedef _Float16 f16x8 __attribute__((ext_vector_type(8)));
typedef float    f32x4 __attribute__((ext_vector_type(4)));

union Frag8 { f16x2 p[4]; f16x8 v; uint4 u; _Float16 h[8]; };

// ---- Kernel P: frag-ordered f16 A panels (1 KB each; 98 KB total) ----
__global__ __launch_bounds__(64)
void build_A(const float* __restrict__ corr, const float* __restrict__ w,
             unsigned short* __restrict__ cwA)
{
    const int p    = blockIdx.x;          // 0..97
    const int lane = threadIdx.x;
    const int gl   = lane & 15;           // state (A row)
    const int q    = lane >> 4;
    Frag8 v;
    if (p < NPAIR) {
        const int dh = (p >= 64);
        const int c  = dh ? p - 32 : p;
        const int d0 = dh * 32 + q * 8;
        const float wc = w[gl * C_TYPES + c];
        const float4 c0 = *(const float4*)(corr + c * C_TYPES + d0);
        const float4 c1 = *(const float4*)(corr + c * C_TYPES + d0 + 4);
        const float4 w0 = *(const float4*)(w + gl * C_TYPES + d0);
        const float4 w1 = *(const float4*)(w + gl * C_TYPES + d0 + 4);
        const float cv[8] = {c0.x,c0.y,c0.z,c0.w,c1.x,c1.y,c1.z,c1.w};
        const float wv[8] = {w0.x,w0.y,w0.z,w0.w,w1.x,w1.y,w1.z,w1.w};
#pragma unroll
        for (int j = 0; j < 8; ++j) {
            const int d = d0 + j;
            const float sc = (d < c) ? 2.0f : (d == c ? 1.0f : 0.0f);
            v.h[j] = (_Float16)(sc * cv[j] * wc * wv[j]);
        }
    } else {                               // W panels for the Ssum GEMM
        const int k0 = (p - NPAIR) * 32 + q * 8;
        const float4 w0 = *(const float4*)(w + gl * C_TYPES + k0);
        const float4 w1 = *(const float4*)(w + gl * C_TYPES + k0 + 4);
        const float wv[8] = {w0.x,w0.y,w0.z,w0.w,w1.x,w1.y,w1.z,w1.w};
#pragma unroll
        for (int j = 0; j < 8; ++j) v.h[j] = (_Float16)wv[j];
    }
    *(uint4*)(cwA + (p << 9) + lane * 8) = v.u;
}

// ---- Kernel M: main ----
__global__ __launch_bounds__(256, 3)
void lognorm_main(const float* __restrict__ Z_mu,
                  const float* __restrict__ Z_sigma,
                  const unsigned short* __restrict__ cwA,
                  float* __restrict__ out)
{
    __shared__ f16x2 x2pT[32][35];   // [gene][d-pair]; stride 35: ~2-way
    __shared__ f16x2 x1pT[32][35];
    __shared__ f16x2 x2tp[C_TYPES][21];  // [c][(g,g+16) pair]; broadcast reads
    __shared__ float accs[4][S_STATES][33];
    __shared__ float ssum_s[S_STATES][33];

    const int gt    = blockIdx.x;    // 0..624, 32 genes (exact)
    const int tid   = threadIdx.x;
    const int w     = tid >> 6;      // wave id = K-interleave slot
    const int lane  = tid & 63;
    const int gl    = lane & 15;
    const int q     = lane >> 4;
    const int gbase = gt * 32;

    // ---- X-phase: thread -> (d-pair dp = tid>>3, genes 2gq,2gq+1 in BOTH
    //      subtiles), 8 exps; writes d-paired, subtile-paired f16 ----
    {
        const int dp = tid >> 3;
        const int gq = tid & 7;
        const int ga = gq * 2;
        const float* zm0 = Z_mu    + (2*dp) * G_GENES + gbase + ga;
        const float* zs0 = Z_sigma + (2*dp) * G_GENES + gbase + ga;
        const float2 m00 = *(const float2*)zm0;
        const float2 m01 = *(const float2*)(zm0 + 16);
        const float2 m10 = *(const float2*)(zm0 + G_GENES);
        const float2 m11 = *(const float2*)(zm0 + G_GENES + 16);
        const float2 s00 = *(const float2*)zs0;
        const float2 s01 = *(const float2*)(zs0 + 16);
        const float2 s10 = *(const float2*)(zs0 + G_GENES);
        const float2 s11 = *(const float2*)(zs0 + G_GENES + 16);
        float x1v[2][2][2], x2v[2][2][2];   // [row r][half h][gene j]
#define XDO(r,h,j,M,S) { const float s_=(S); const float e_=__expf(fmaf(0.5f*s_,s_,(M)))*0.25f; \
                         x1v[r][h][j]=e_; x2v[r][h][j]=e_*s_; }
        XDO(0,0,0, m00.x, s00.x) XDO(0,0,1, m00.y, s00.y)
        XDO(0,1,0, m01.x, s01.x) XDO(0,1,1, m01.y, s01.y)
        XDO(1,0,0, m10.x, s10.x) XDO(1,0,1, m10.y, s10.y)
        XDO(1,1,0, m11.x, s11.x) XDO(1,1,1, m11.y, s11.y)
#undef XDO
#pragma unroll
        for (int h = 0; h < 2; ++h)
#pragma unroll
            for (int j = 0; j < 2; ++j) {
                const int g = ga + j + 16 * h;
                f16x2 a, b;
                a.x = (_Float16)x2v[0][h][j]; a.y = (_Float16)x2v[1][h][j];
                b.x = (_Float16)x1v[0][h][j]; b.y = (_Float16)x1v[1][h][j];
                x2pT[g][dp] = a;
                x1pT[g][dp] = b;
            }
#pragma unroll
        for (int r = 0; r < 2; ++r)
#pragma unroll
            for (int j = 0; j < 2; ++j) {
                f16x2 a;
                a.x = (_Float16)x2v[r][0][j];   // gene gp
                a.y = (_Float16)x2v[r][1][j];   // gene gp+16
                x2tp[2*dp + r][ga + j] = a;
            }
    }
    __syncthreads();

    // ---- B sources: 16 + 24 LDS b32 reads, all ~free of conflicts ----
    f16x2 xh[2][4][2];                  // [dh][jp][t]
#pragma unroll
    for (int dh = 0; dh < 2; ++dh)
#pragma unroll
        for (int t = 0; t < 2; ++t)
#pragma unroll
            for (int jp = 0; jp < 4; ++jp)
                xh[dh][jp][t] = x2pT[gl + 16*t][dh*16 + q*4 + jp];

    f16x2 xct[PER_WAVE];                // (t0,t1) pair per c_i; broadcast
#pragma unroll
    for (int i = 0; i < PER_WAVE; ++i) {
        const int c = i*4 + w - ((i >= 16) ? 32 : 0);
        xct[i] = x2tp[c][gl];
    }

    // ---- K-loop: 24 x {A-load(b128), 8 pk_mul, 2 MFMA} ----
    const unsigned short* Abase = cwA + (w << 9) + lane * 8;
    f32x4 acc0 = {0.f,0.f,0.f,0.f}, acc1 = {0.f,0.f,0.f,0.f};
#pragma unroll
    for (int i = 0; i < PER_WAVE; ++i) {
        Frag8 af; af.u = *(const uint4*)(Abase + (i << 11));
        const int dh = (i >= 16) ? 1 : 0;
        Frag8 b0, b1;
#pragma unroll
        for (int jp = 0; jp < 4; ++jp) {
            f16x2 s0; s0.x = xct[i].x; s0.y = xct[i].x;   // op_sel splat
            f16x2 s1; s1.x = xct[i].y; s1.y = xct[i].y;
            b0.p[jp] = s0 * xh[dh][jp][0];
            b1.p[jp] = s1 * xh[dh][jp][1];
        }
        acc0 = __builtin_amdgcn_mfma_f32_16x16x32_f16(af.v, b0.v, acc0, 0, 0, 0);
        acc1 = __builtin_amdgcn_mfma_f32_16x16x32_f16(af.v, b1.v, acc1, 0, 0, 0);
    }
#pragma unroll
    for (int r = 0; r < 4; ++r) {
        accs[w][q*4 + r][gl]      = acc0[r];
        accs[w][q*4 + r][gl + 16] = acc1[r];
    }

    // ---- Ssum GEMM: waves 0,1 -> gene subtiles 0,1 ----
    if (w < 2) {
        Frag8 x1f[2], wf[2];
#pragma unroll
        for (int kk = 0; kk < 2; ++kk) {
            wf[kk].u = *(const uint4*)(cwA + ((NPAIR + kk) << 9) + lane * 8);
#pragma unroll
            for (int jp = 0; jp < 4; ++jp)
                x1f[kk].p[jp] = x1pT[gl + 16*w][kk*16 + q*4 + jp];
        }
        f32x4 sa = {0.f,0.f,0.f,0.f};
        sa = __builtin_amdgcn_mfma_f32_16x16x32_f16(wf[0].v, x1f[0].v, sa, 0, 0, 0);
        sa = __builtin_amdgcn_mfma_f32_16x16x32_f16(wf[1].v, x1f[1].v, sa, 0, 0, 0);
#pragma unroll
        for (int r = 0; r < 4; ++r) ssum_s[q*4 + r][gl + 16*w] = sa[r];
    }
    __syncthreads();

    // ---- epilogue: thread -> (s = tid>>4, genes gx, gx+16) ----
    const int s  = tid >> 4;
    const int gx = tid & 15;
#pragma unroll
    for (int t = 0; t < 2; ++t) {
        const int gg = gx + 16 * t;
        const float vn = (accs[0][s][gg] + accs[1][s][gg])
                       + (accs[2][s][gg] + accs[3][s][gg]);
        const float ss   = ssum_s[s][gg];                 // = Ssum/4
        const float rvar = fmaxf(vn, 0.f) / (ss * ss);    // scale cancels
        out[s * G_GENES + gbase + gg] =
            __logf(ss) + 1.3862943611f - 0.5f * rvar;     // + log 4
        out[OUT_HALF + s * G_GENES + gbase + gg] = sqrtf(rvar);
    }
}

extern "C" void kernel_launch(void* const* d_in, const int* in_sizes, int n_in,
                              void* d_out, int out_size, void* d_ws, size_t ws_size,
                              hipStream_t stream) {
    const float* Z_mu      = (const float*)d_in[0];
    const float* Z_sigma   = (const float*)d_in[1];
    const float* corr      = (const float*)d_in[2];
    const float* cell_prob = (const float*)d_in[3];
    float* out = (float*)d_out;
    unsigned short* cwA = (unsigned short*)d_ws;   // 98 KB frag-ordered f16 A

    build_A<<<dim3(NPAIR + 2), dim3(64), 0, stream>>>(corr, cell_prob, cwA);

    const int gtiles = G_GENES / 32;               // 625, exact
    lognorm_main<<<dim3(gtiles), dim3(256), 0, stream>>>(
        Z_mu, Z_sigma, cwA, out);
}